// Round 1
// baseline (3149.554 us; speedup 1.0000x reference)
//
#include <hip/hip_runtime.h>
#include <hip/hip_bf16.h>

#define BN_EPS 1e-5f

// ---------------------------------------------------------------------------
// degree: deg[d] += 1 for each edge
__global__ __launch_bounds__(256) void deg_kernel(const int* __restrict__ dst,
                                                  float* __restrict__ deg, int nE) {
    int i = blockIdx.x * 256 + threadIdx.x;
    if (i < nE) unsafeAtomicAdd(&deg[dst[i]], 1.0f);
}

// dinv[i] = rsqrt(deg[i]+1)  (in place over the deg buffer)
__global__ __launch_bounds__(256) void dinv_kernel(float* __restrict__ deg, int n) {
    int i = blockIdx.x * 256 + threadIdx.x;
    if (i < n) deg[i] = rsqrtf(deg[i] + 1.0f);
}

// ---------------------------------------------------------------------------
// edge scatter: out[dst] += feat[src] * dinv[src]*dinv[dst], CH channels
template<int CH>
__global__ __launch_bounds__(256) void agg_scatter(const float* __restrict__ feat,
                                                   const int* __restrict__ src,
                                                   const int* __restrict__ dst,
                                                   const float* __restrict__ dinv,
                                                   float* __restrict__ out, int nE) {
    unsigned idx = blockIdx.x * 256u + threadIdx.x;
    unsigned total = (unsigned)nE * CH;
    if (idx >= total) return;
    unsigned e = idx / CH;
    unsigned c = idx - e * CH;
    int s = src[e], d = dst[e];
    float ne = dinv[s] * dinv[d];
    unsafeAtomicAdd(&out[(size_t)d * CH + c], feat[(size_t)s * CH + c] * ne);
}

// ---------------------------------------------------------------------------
// Fused GEMM (+ optional self-loop combine on input, + optional bias/BN/ReLU)
//   input row = COMBINE ? agg[r] + self[r]*dinv[r]^2 : self[r]
//   out = BNRELU ? relu(bn(in @ W + bias)) : in @ W
template<int IN, int OUT, bool COMBINE, bool BNRELU>
__global__ __launch_bounds__(256) void gemm_bn(const float* __restrict__ agg,
                                               const float* __restrict__ self_,
                                               const float* __restrict__ dinv,
                                               const float* __restrict__ W,
                                               const float* __restrict__ bias,
                                               const float* __restrict__ gg,
                                               const float* __restrict__ bb,
                                               const float* __restrict__ mm,
                                               const float* __restrict__ vv,
                                               float* __restrict__ out, int n) {
    constexpr int ROWS = 16;
    constexpr int RL = 256 / OUT;      // row-lanes: 2 (OUT=128) or 4 (OUT=64)
    constexpr int RPT = ROWS / RL;     // rows per thread
    __shared__ float s_in[ROWS][IN];
    const int r0 = blockIdx.x * ROWS;
    const int tid = threadIdx.x;

    // stage combined input rows into LDS (completes before any global write,
    // so self_ == out (in-place) is safe)
    for (int idx = tid; idx < ROWS * IN; idx += 256) {
        int rr = idx / IN, k = idx - rr * IN;
        int row = r0 + rr;
        float val = 0.0f;
        if (row < n) {
            if constexpr (COMBINE) {
                float dv = dinv[row];
                val = agg[(size_t)row * IN + k] + self_[(size_t)row * IN + k] * dv * dv;
            } else {
                val = self_[(size_t)row * IN + k];
            }
        }
        s_in[rr][k] = val;
    }
    __syncthreads();

    const int c = tid % OUT;
    const int lr = tid / OUT;
    float acc[RPT];
#pragma unroll
    for (int j = 0; j < RPT; j++) acc[j] = 0.0f;

    for (int k = 0; k < IN; k++) {
        float w = W[k * OUT + c];
#pragma unroll
        for (int j = 0; j < RPT; j++) acc[j] += s_in[lr + j * RL][k] * w;
    }

    float scale = 1.0f, shift = 0.0f;
    if constexpr (BNRELU) {
        scale = gg[c] * rsqrtf(vv[c] + BN_EPS);
        shift = bb[c] + (bias[c] - mm[c]) * scale;
    }
#pragma unroll
    for (int j = 0; j < RPT; j++) {
        int row = r0 + lr + j * RL;
        if (row < n) {
            float val = acc[j];
            if constexpr (BNRELU) val = fmaxf(val * scale + shift, 0.0f);
            out[(size_t)row * OUT + c] = val;
        }
    }
}

// ---------------------------------------------------------------------------
// per-graph node count
__global__ __launch_bounds__(256) void count_kernel(const int* __restrict__ batch,
                                                    float* __restrict__ cnt, int n) {
    int i = blockIdx.x * 256 + threadIdx.x;
    if (i < n) unsafeAtomicAdd(&cnt[batch[i]], 1.0f);
}

// layer-2 tail: h = relu(bn(agg + xw*dinv^2 + b2)); pool[batch] += h   (64 ch)
__global__ __launch_bounds__(256) void final_node_kernel(const float* __restrict__ aggB,
                                                         const float* __restrict__ xwA,
                                                         const float* __restrict__ dinv,
                                                         const float* __restrict__ bias,
                                                         const float* __restrict__ gg,
                                                         const float* __restrict__ bb,
                                                         const float* __restrict__ mm,
                                                         const float* __restrict__ vv,
                                                         const int* __restrict__ batch,
                                                         float* __restrict__ pool, int n) {
    unsigned idx = blockIdx.x * 256u + threadIdx.x;
    if (idx >= (unsigned)n * 64u) return;
    unsigned i = idx >> 6, c = idx & 63u;
    float dv = dinv[i];
    float h = aggB[idx] + xwA[idx] * dv * dv + bias[c];
    float scale = gg[c] * rsqrtf(vv[c] + BN_EPS);
    float val = fmaxf((h - mm[c]) * scale + bb[c], 0.0f);
    unsafeAtomicAdd(&pool[(size_t)batch[i] * 64 + c], val);
}

// ---------------------------------------------------------------------------
// per-graph MLP head: 64 -> relu(128) -> relu(64) -> 2
__global__ __launch_bounds__(128) void fc_head_kernel(const float* __restrict__ pool,
                                                      const float* __restrict__ cnt,
                                                      const float* __restrict__ fw0,
                                                      const float* __restrict__ fb0,
                                                      const float* __restrict__ fw1,
                                                      const float* __restrict__ fb1,
                                                      const float* __restrict__ ow,
                                                      const float* __restrict__ ob,
                                                      float* __restrict__ out) {
    int g = blockIdx.x, tid = threadIdx.x;
    __shared__ float p[64], h1[128], h2[64];
    if (tid < 64) p[tid] = pool[g * 64 + tid] / fmaxf(cnt[g], 1.0f);
    __syncthreads();
    {
        float acc = fb0[tid];
        for (int k = 0; k < 64; k++) acc += p[k] * fw0[k * 128 + tid];
        h1[tid] = fmaxf(acc, 0.0f);
    }
    __syncthreads();
    if (tid < 64) {
        float acc = fb1[tid];
        for (int k = 0; k < 128; k++) acc += h1[k] * fw1[k * 64 + tid];
        h2[tid] = fmaxf(acc, 0.0f);
    }
    __syncthreads();
    if (tid < 2) {
        float acc = ob[tid];
        for (int k = 0; k < 64; k++) acc += h2[k] * ow[k * 2 + tid];
        out[g * 2 + tid] = acc;
    }
}

// ---------------------------------------------------------------------------
extern "C" void kernel_launch(void* const* d_in, const int* in_sizes, int n_in,
                              void* d_out, int out_size, void* d_ws, size_t ws_size,
                              hipStream_t stream) {
    const float* x     = (const float*)d_in[0];
    const int*   eidx  = (const int*)d_in[1];
    const int*   batch = (const int*)d_in[2];
    const float* w0 = (const float*)d_in[4];
    const float* b0 = (const float*)d_in[5];
    const float* g0 = (const float*)d_in[6];
    const float* be0 = (const float*)d_in[7];
    const float* m0 = (const float*)d_in[8];
    const float* v0 = (const float*)d_in[9];
    const float* w1 = (const float*)d_in[10];
    const float* b1 = (const float*)d_in[11];
    const float* g1 = (const float*)d_in[12];
    const float* be1 = (const float*)d_in[13];
    const float* m1 = (const float*)d_in[14];
    const float* v1 = (const float*)d_in[15];
    const float* w2 = (const float*)d_in[16];
    const float* b2 = (const float*)d_in[17];
    const float* g2 = (const float*)d_in[18];
    const float* be2 = (const float*)d_in[19];
    const float* m2 = (const float*)d_in[20];
    const float* v2 = (const float*)d_in[21];
    const float* fw0 = (const float*)d_in[22];
    const float* fb0 = (const float*)d_in[23];
    const float* fw1 = (const float*)d_in[24];
    const float* fb1 = (const float*)d_in[25];
    const float* ow = (const float*)d_in[26];
    const float* ob = (const float*)d_in[27];

    const int N = in_sizes[0] / 36;
    const int E = in_sizes[1] / 2;
    const int G = out_size / 2;
    const int* src = eidx;
    const int* dst = eidx + E;

    float* ws = (float*)d_ws;
    float* dinv = ws;                               // N (deg, then dinv)
    float* A    = ws + (((size_t)N + 127) & ~127ul); // N*128
    float* B    = A + (size_t)N * 128;               // N*128
    float* pool = B + (size_t)N * 128;               // G*64
    float* cnt  = pool + (size_t)G * 64;             // G

    // degree + dinv
    hipMemsetAsync(dinv, 0, (size_t)N * 4, stream);
    deg_kernel<<<(E + 255) / 256, 256, 0, stream>>>(dst, dinv, E);
    dinv_kernel<<<(N + 255) / 256, 256, 0, stream>>>(dinv, N);

    // ---- layer 0: aggregate 36-dim input, then GEMM 36->128 + BN + ReLU -> B
    hipMemsetAsync(A, 0, (size_t)N * 36 * 4, stream);
    {
        unsigned total = (unsigned)E * 36u;
        agg_scatter<36><<<(total + 255) / 256, 256, 0, stream>>>(x, src, dst, dinv, A, E);
    }
    gemm_bn<36, 128, true, true><<<(N + 15) / 16, 256, 0, stream>>>(
        A, x, dinv, w0, b0, g0, be0, m0, v0, B, N);

    // ---- layer 1: aggregate 128-dim B -> A, then GEMM 128->128 + BN + ReLU -> B (in place)
    hipMemsetAsync(A, 0, (size_t)N * 128 * 4, stream);
    {
        unsigned total = (unsigned)E * 128u;
        agg_scatter<128><<<(total + 255) / 256, 256, 0, stream>>>(B, src, dst, dinv, A, E);
    }
    gemm_bn<128, 128, true, true><<<(N + 15) / 16, 256, 0, stream>>>(
        A, B, dinv, w1, b1, g1, be1, m1, v1, B, N);

    // ---- layer 2: GEMM first (128->64, raw xw) -> A, aggregate 64-dim -> B
    gemm_bn<128, 64, false, false><<<(N + 15) / 16, 256, 0, stream>>>(
        nullptr, B, nullptr, w2, nullptr, nullptr, nullptr, nullptr, nullptr, A, N);
    hipMemsetAsync(B, 0, (size_t)N * 64 * 4, stream);
    {
        unsigned total = (unsigned)E * 64u;
        agg_scatter<64><<<(total + 255) / 256, 256, 0, stream>>>(A, src, dst, dinv, B, E);
    }

    // ---- pool (mean over batch) with fused bias+BN+ReLU
    hipMemsetAsync(pool, 0, (size_t)G * 64 * 4, stream);
    hipMemsetAsync(cnt, 0, (size_t)G * 4, stream);
    count_kernel<<<(N + 255) / 256, 256, 0, stream>>>(batch, cnt, N);
    {
        unsigned total = (unsigned)N * 64u;
        final_node_kernel<<<(total + 255) / 256, 256, 0, stream>>>(
            B, A, dinv, b2, g2, be2, m2, v2, batch, pool, N);
    }

    // ---- MLP head
    fc_head_kernel<<<G, 128, 0, stream>>>(pool, cnt, fw0, fb0, fw1, fb1, ow, ob, (float*)d_out);
}

// Round 2
// 1178.661 us; speedup vs baseline: 2.6721x; 2.6721x over previous
//
#include <hip/hip_runtime.h>
#include <hip/hip_bf16.h>

#define BN_EPS 1e-5f

// ---------------------------------------------------------------------------
// degree count (int atomics)
__global__ __launch_bounds__(256) void deg_count_kernel(const int* __restrict__ dst,
                                                        int* __restrict__ degI, int nE) {
    int i = blockIdx.x * 256 + threadIdx.x;
    if (i < nE) atomicAdd(&degI[dst[i]], 1);
}

// dinv[i] = rsqrt(deg[i]+1)
__global__ __launch_bounds__(256) void dinv_kernel(const int* __restrict__ degI,
                                                   float* __restrict__ dinv, int n) {
    int i = blockIdx.x * 256 + threadIdx.x;
    if (i < n) dinv[i] = rsqrtf((float)degI[i] + 1.0f);
}

// ---------------------------------------------------------------------------
// exclusive scan of degI -> row_start (3 phases)
__global__ __launch_bounds__(256) void scan_block(const int* __restrict__ degI,
                                                  int* __restrict__ ex,
                                                  int* __restrict__ bsum, int n) {
    __shared__ int tmp[256];
    int tid = threadIdx.x;
    int i = blockIdx.x * 256 + tid;
    int v = (i < n) ? degI[i] : 0;
    tmp[tid] = v;
    __syncthreads();
    for (int off = 1; off < 256; off <<= 1) {
        int t = (tid >= off) ? tmp[tid - off] : 0;
        __syncthreads();
        tmp[tid] += t;
        __syncthreads();
    }
    if (i < n) ex[i] = tmp[tid] - v;            // exclusive within block
    if (tid == 255) bsum[blockIdx.x] = tmp[255]; // block total
}

__global__ __launch_bounds__(512) void scan_bsum(int* __restrict__ bsum, int nb) {
    __shared__ int tmp[512];
    int tid = threadIdx.x;
    int v = (tid < nb) ? bsum[tid] : 0;
    tmp[tid] = v;
    __syncthreads();
    for (int off = 1; off < 512; off <<= 1) {
        int t = (tid >= off) ? tmp[tid - off] : 0;
        __syncthreads();
        tmp[tid] += t;
        __syncthreads();
    }
    if (tid < nb) bsum[tid] = tmp[tid] - v;      // exclusive block offsets
}

__global__ __launch_bounds__(256) void scan_add(int* __restrict__ ex,
                                                const int* __restrict__ bsum, int n) {
    int i = blockIdx.x * 256 + threadIdx.x;
    if (i < n) ex[i] += bsum[blockIdx.x];
}

// ---------------------------------------------------------------------------
// CSR fill: place each edge's src into its dst's segment
__global__ __launch_bounds__(256) void fill_csr(const int* __restrict__ src,
                                                const int* __restrict__ dst,
                                                const int* __restrict__ row_start,
                                                int* __restrict__ cursor,
                                                int* __restrict__ src_sorted, int nE) {
    int i = blockIdx.x * 256 + threadIdx.x;
    if (i < nE) {
        int d = dst[i];
        int pos = row_start[d] + atomicAdd(&cursor[d], 1);
        src_sorted[pos] = src[i];
    }
}

// ---------------------------------------------------------------------------
// pull aggregation with fused self-loop:
//   out[i,c] = dinv_i * ( dinv_i*feat[i,c] + sum_e dinv_s*feat[s,c] )
template<int CH>
__global__ __launch_bounds__(256) void agg_pull(const float* __restrict__ feat,
                                                const int* __restrict__ row_start,
                                                const int* __restrict__ degI,
                                                const int* __restrict__ src_sorted,
                                                const float* __restrict__ dinv,
                                                float* __restrict__ out, int n) {
    unsigned idx = blockIdx.x * 256u + threadIdx.x;
    if (idx >= (unsigned)n * CH) return;
    unsigned i = idx / CH;
    unsigned c = idx - i * CH;
    int e = row_start[i];
    const int re = e + degI[i];
    float di = dinv[i];
    float acc = di * feat[(size_t)i * CH + c];   // self-loop (outer di applied at end)
    for (; e + 3 < re; e += 4) {
        int s0 = src_sorted[e], s1 = src_sorted[e + 1],
            s2 = src_sorted[e + 2], s3 = src_sorted[e + 3];
        float w0 = dinv[s0], w1 = dinv[s1], w2 = dinv[s2], w3 = dinv[s3];
        float f0 = feat[(size_t)s0 * CH + c], f1 = feat[(size_t)s1 * CH + c],
              f2 = feat[(size_t)s2 * CH + c], f3 = feat[(size_t)s3 * CH + c];
        acc += f0 * w0 + f1 * w1 + f2 * w2 + f3 * w3;
    }
    for (; e < re; e++) {
        int s = src_sorted[e];
        acc += feat[(size_t)s * CH + c] * dinv[s];
    }
    out[idx] = acc * di;
}

// ---------------------------------------------------------------------------
// GEMM (+ optional bias/BN/ReLU). Input already contains the combined feature.
template<int IN, int OUT, bool BNRELU>
__global__ __launch_bounds__(256) void gemm_bn(const float* __restrict__ in,
                                               const float* __restrict__ W,
                                               const float* __restrict__ bias,
                                               const float* __restrict__ gg,
                                               const float* __restrict__ bb,
                                               const float* __restrict__ mm,
                                               const float* __restrict__ vv,
                                               float* __restrict__ out, int n) {
    constexpr int ROWS = 16;
    constexpr int RL = 256 / OUT;      // row-lanes: 2 (OUT=128) or 4 (OUT=64)
    constexpr int RPT = ROWS / RL;     // rows per thread
    __shared__ float s_in[ROWS][IN];
    const int r0 = blockIdx.x * ROWS;
    const int tid = threadIdx.x;

    for (int idx = tid; idx < ROWS * IN; idx += 256) {
        int rr = idx / IN, k = idx - rr * IN;
        int row = r0 + rr;
        s_in[rr][k] = (row < n) ? in[(size_t)row * IN + k] : 0.0f;
    }
    __syncthreads();

    const int c = tid % OUT;
    const int lr = tid / OUT;
    float acc[RPT];
#pragma unroll
    for (int j = 0; j < RPT; j++) acc[j] = 0.0f;

    for (int k = 0; k < IN; k++) {
        float w = W[k * OUT + c];
#pragma unroll
        for (int j = 0; j < RPT; j++) acc[j] += s_in[lr + j * RL][k] * w;
    }

    float scale = 1.0f, shift = 0.0f;
    if constexpr (BNRELU) {
        scale = gg[c] * rsqrtf(vv[c] + BN_EPS);
        shift = bb[c] + (bias[c] - mm[c]) * scale;
    }
#pragma unroll
    for (int j = 0; j < RPT; j++) {
        int row = r0 + lr + j * RL;
        if (row < n) {
            float val = acc[j];
            if constexpr (BNRELU) val = fmaxf(val * scale + shift, 0.0f);
            out[(size_t)row * OUT + c] = val;
        }
    }
}

// ---------------------------------------------------------------------------
// per-graph node count
__global__ __launch_bounds__(256) void count_kernel(const int* __restrict__ batch,
                                                    float* __restrict__ cnt, int n) {
    int i = blockIdx.x * 256 + threadIdx.x;
    if (i < n) unsafeAtomicAdd(&cnt[batch[i]], 1.0f);
}

// layer-2 tail: h = relu(bn(aggB + b2)); pool[batch] += h   (64 ch)
__global__ __launch_bounds__(256) void final_node_kernel(const float* __restrict__ aggB,
                                                         const float* __restrict__ bias,
                                                         const float* __restrict__ gg,
                                                         const float* __restrict__ bb,
                                                         const float* __restrict__ mm,
                                                         const float* __restrict__ vv,
                                                         const int* __restrict__ batch,
                                                         float* __restrict__ pool, int n) {
    unsigned idx = blockIdx.x * 256u + threadIdx.x;
    if (idx >= (unsigned)n * 64u) return;
    unsigned i = idx >> 6, c = idx & 63u;
    float h = aggB[idx] + bias[c];
    float scale = gg[c] * rsqrtf(vv[c] + BN_EPS);
    float val = fmaxf((h - mm[c]) * scale + bb[c], 0.0f);
    unsafeAtomicAdd(&pool[(size_t)batch[i] * 64 + c], val);
}

// ---------------------------------------------------------------------------
// per-graph MLP head: 64 -> relu(128) -> relu(64) -> 2
__global__ __launch_bounds__(128) void fc_head_kernel(const float* __restrict__ pool,
                                                      const float* __restrict__ cnt,
                                                      const float* __restrict__ fw0,
                                                      const float* __restrict__ fb0,
                                                      const float* __restrict__ fw1,
                                                      const float* __restrict__ fb1,
                                                      const float* __restrict__ ow,
                                                      const float* __restrict__ ob,
                                                      float* __restrict__ out) {
    int g = blockIdx.x, tid = threadIdx.x;
    __shared__ float p[64], h1[128], h2[64];
    if (tid < 64) p[tid] = pool[g * 64 + tid] / fmaxf(cnt[g], 1.0f);
    __syncthreads();
    {
        float acc = fb0[tid];
        for (int k = 0; k < 64; k++) acc += p[k] * fw0[k * 128 + tid];
        h1[tid] = fmaxf(acc, 0.0f);
    }
    __syncthreads();
    if (tid < 64) {
        float acc = fb1[tid];
        for (int k = 0; k < 128; k++) acc += h1[k] * fw1[k * 64 + tid];
        h2[tid] = fmaxf(acc, 0.0f);
    }
    __syncthreads();
    if (tid < 2) {
        float acc = ob[tid];
        for (int k = 0; k < 64; k++) acc += h2[k] * ow[k * 2 + tid];
        out[g * 2 + tid] = acc;
    }
}

// ---------------------------------------------------------------------------
extern "C" void kernel_launch(void* const* d_in, const int* in_sizes, int n_in,
                              void* d_out, int out_size, void* d_ws, size_t ws_size,
                              hipStream_t stream) {
    const float* x     = (const float*)d_in[0];
    const int*   eidx  = (const int*)d_in[1];
    const int*   batch = (const int*)d_in[2];
    const float* w0 = (const float*)d_in[4];
    const float* b0 = (const float*)d_in[5];
    const float* g0 = (const float*)d_in[6];
    const float* be0 = (const float*)d_in[7];
    const float* m0 = (const float*)d_in[8];
    const float* v0 = (const float*)d_in[9];
    const float* w1 = (const float*)d_in[10];
    const float* b1 = (const float*)d_in[11];
    const float* g1 = (const float*)d_in[12];
    const float* be1 = (const float*)d_in[13];
    const float* m1 = (const float*)d_in[14];
    const float* v1 = (const float*)d_in[15];
    const float* w2 = (const float*)d_in[16];
    const float* b2 = (const float*)d_in[17];
    const float* g2 = (const float*)d_in[18];
    const float* be2 = (const float*)d_in[19];
    const float* m2 = (const float*)d_in[20];
    const float* v2 = (const float*)d_in[21];
    const float* fw0 = (const float*)d_in[22];
    const float* fb0 = (const float*)d_in[23];
    const float* fw1 = (const float*)d_in[24];
    const float* fb1 = (const float*)d_in[25];
    const float* ow = (const float*)d_in[26];
    const float* ob = (const float*)d_in[27];

    const int N = in_sizes[0] / 36;
    const int E = in_sizes[1] / 2;
    const int G = out_size / 2;
    const int* src = eidx;
    const int* dst = eidx + E;

    const int NB = (N + 255) / 256;   // scan blocks (must be <= 512)

    // ---- workspace layout (4-byte units)
    char* wsb = (char*)d_ws;
    int*   degI       = (int*)wsb;                       wsb += (size_t)N * 4;
    int*   row_start  = (int*)wsb;                       wsb += (size_t)N * 4;
    int*   cursor     = (int*)wsb;                       wsb += (size_t)N * 4;
    int*   bsum       = (int*)wsb;                       wsb += 512 * 4;
    int*   src_sorted = (int*)wsb;                       wsb += (size_t)E * 4;
    float* dinv       = (float*)wsb;                     wsb += (size_t)N * 4;
    float* A          = (float*)wsb;                     wsb += (size_t)N * 128 * 4;
    float* B          = (float*)wsb;                     wsb += (size_t)N * 128 * 4;
    float* pool       = (float*)wsb;                     wsb += (size_t)G * 64 * 4;
    float* cnt        = (float*)wsb;

    // ---- degree, dinv, CSR
    hipMemsetAsync(degI, 0, (size_t)N * 4, stream);
    hipMemsetAsync(cursor, 0, (size_t)N * 4, stream);
    deg_count_kernel<<<(E + 255) / 256, 256, 0, stream>>>(dst, degI, E);
    dinv_kernel<<<NB, 256, 0, stream>>>(degI, dinv, N);
    scan_block<<<NB, 256, 0, stream>>>(degI, row_start, bsum, N);
    scan_bsum<<<1, 512, 0, stream>>>(bsum, NB);
    scan_add<<<NB, 256, 0, stream>>>(row_start, bsum, N);
    fill_csr<<<(E + 255) / 256, 256, 0, stream>>>(src, dst, row_start, cursor, src_sorted, E);

    // ---- layer 0: pull 36-ch (x -> A), GEMM 36->128 +BN+ReLU (A -> B)
    {
        unsigned total = (unsigned)N * 36u;
        agg_pull<36><<<(total + 255) / 256, 256, 0, stream>>>(x, row_start, degI, src_sorted, dinv, A, N);
    }
    gemm_bn<36, 128, true><<<(N + 15) / 16, 256, 0, stream>>>(A, w0, b0, g0, be0, m0, v0, B, N);

    // ---- layer 1: pull 128-ch (B -> A), GEMM 128->128 +BN+ReLU (A -> B)
    {
        unsigned total = (unsigned)N * 128u;
        agg_pull<128><<<(total + 255) / 256, 256, 0, stream>>>(B, row_start, degI, src_sorted, dinv, A, N);
    }
    gemm_bn<128, 128, true><<<(N + 15) / 16, 256, 0, stream>>>(A, w1, b1, g1, be1, m1, v1, B, N);

    // ---- layer 2: GEMM 128->64 raw (B -> A), pull 64-ch (A -> B)
    gemm_bn<128, 64, false><<<(N + 15) / 16, 256, 0, stream>>>(B, w2, nullptr, nullptr, nullptr, nullptr, nullptr, A, N);
    {
        unsigned total = (unsigned)N * 64u;
        agg_pull<64><<<(total + 255) / 256, 256, 0, stream>>>(A, row_start, degI, src_sorted, dinv, B, N);
    }

    // ---- pool (mean over batch) with fused bias+BN+ReLU
    hipMemsetAsync(pool, 0, (size_t)G * 64 * 4, stream);
    hipMemsetAsync(cnt, 0, (size_t)G * 4, stream);
    count_kernel<<<NB, 256, 0, stream>>>(batch, cnt, N);
    {
        unsigned total = (unsigned)N * 64u;
        final_node_kernel<<<(total + 255) / 256, 256, 0, stream>>>(B, b2, g2, be2, m2, v2, batch, pool, N);
    }

    // ---- MLP head
    fc_head_kernel<<<G, 128, 0, stream>>>(pool, cnt, fw0, fb0, fw1, fb1, ow, ob, (float*)d_out);
}

// Round 3
// 1133.710 us; speedup vs baseline: 2.7781x; 1.0396x over previous
//
#include <hip/hip_runtime.h>
#include <hip/hip_bf16.h>

#define BN_EPS 1e-5f

// ---------------------------------------------------------------------------
// degree count (int atomics)
__global__ __launch_bounds__(256) void deg_count_kernel(const int* __restrict__ dst,
                                                        int* __restrict__ degI, int nE) {
    int i = blockIdx.x * 256 + threadIdx.x;
    if (i < nE) atomicAdd(&degI[dst[i]], 1);
}

// dinv[i] = rsqrt(deg[i]+1)
__global__ __launch_bounds__(256) void dinv_kernel(const int* __restrict__ degI,
                                                   float* __restrict__ dinv, int n) {
    int i = blockIdx.x * 256 + threadIdx.x;
    if (i < n) dinv[i] = rsqrtf((float)degI[i] + 1.0f);
}

// ---------------------------------------------------------------------------
// exclusive scan of degI -> row_start (3 phases)
__global__ __launch_bounds__(256) void scan_block(const int* __restrict__ degI,
                                                  int* __restrict__ ex,
                                                  int* __restrict__ bsum, int n) {
    __shared__ int tmp[256];
    int tid = threadIdx.x;
    int i = blockIdx.x * 256 + tid;
    int v = (i < n) ? degI[i] : 0;
    tmp[tid] = v;
    __syncthreads();
    for (int off = 1; off < 256; off <<= 1) {
        int t = (tid >= off) ? tmp[tid - off] : 0;
        __syncthreads();
        tmp[tid] += t;
        __syncthreads();
    }
    if (i < n) ex[i] = tmp[tid] - v;
    if (tid == 255) bsum[blockIdx.x] = tmp[255];
}

__global__ __launch_bounds__(512) void scan_bsum(int* __restrict__ bsum, int nb) {
    __shared__ int tmp[512];
    int tid = threadIdx.x;
    int v = (tid < nb) ? bsum[tid] : 0;
    tmp[tid] = v;
    __syncthreads();
    for (int off = 1; off < 512; off <<= 1) {
        int t = (tid >= off) ? tmp[tid - off] : 0;
        __syncthreads();
        tmp[tid] += t;
        __syncthreads();
    }
    if (tid < nb) bsum[tid] = tmp[tid] - v;
}

__global__ __launch_bounds__(256) void scan_add(int* __restrict__ ex,
                                                const int* __restrict__ bsum, int n) {
    int i = blockIdx.x * 256 + threadIdx.x;
    if (i < n) ex[i] += bsum[blockIdx.x];
}

// ---------------------------------------------------------------------------
// CSR fill: place each edge's src into its dst's segment
__global__ __launch_bounds__(256) void fill_csr(const int* __restrict__ src,
                                                const int* __restrict__ dst,
                                                const int* __restrict__ row_start,
                                                int* __restrict__ cursor,
                                                int* __restrict__ src_sorted, int nE) {
    int i = blockIdx.x * 256 + threadIdx.x;
    if (i < nE) {
        int d = dst[i];
        int pos = row_start[d] + atomicAdd(&cursor[d], 1);
        src_sorted[pos] = src[i];
    }
}

// ---------------------------------------------------------------------------
// layer-0 pull (36-ch, input x unscaled, dinv gathered per edge):
//   out[i,c] = dinv_i * ( dinv_i*x[i,c] + sum_e dinv_s*x[s,c] )
__global__ __launch_bounds__(256) void agg_pull36(const float* __restrict__ feat,
                                                  const int* __restrict__ row_start,
                                                  const int* __restrict__ degI,
                                                  const int* __restrict__ src_sorted,
                                                  const float* __restrict__ dinv,
                                                  float* __restrict__ out, int n) {
    unsigned idx = blockIdx.x * 256u + threadIdx.x;
    if (idx >= (unsigned)n * 36u) return;
    unsigned i = idx / 36u;
    unsigned c = idx - i * 36u;
    int e = row_start[i];
    const int re = e + degI[i];
    float di = dinv[i];
    float acc = di * feat[(size_t)i * 36 + c];
    for (; e + 3 < re; e += 4) {
        int s0 = src_sorted[e], s1 = src_sorted[e + 1],
            s2 = src_sorted[e + 2], s3 = src_sorted[e + 3];
        float w0 = dinv[s0], w1 = dinv[s1], w2 = dinv[s2], w3 = dinv[s3];
        float f0 = feat[(size_t)s0 * 36 + c], f1 = feat[(size_t)s1 * 36 + c],
              f2 = feat[(size_t)s2 * 36 + c], f3 = feat[(size_t)s3 * 36 + c];
        acc += f0 * w0 + f1 * w1 + f2 * w2 + f3 * w3;
    }
    for (; e < re; e++) {
        int s = src_sorted[e];
        acc += feat[(size_t)s * 36 + c] * dinv[s];
    }
    out[idx] = acc * di;
}

// ---------------------------------------------------------------------------
// wave-per-node pull over PRE-SCALED features (feat_s = dinv .* h):
//   out[i] = dinv_i * ( feat_s[i] + sum_{s in N(i)} feat_s[s] )
// VEC=2 -> CH=128 (float2/lane), VEC=1 -> CH=64 (float/lane)
template<int VEC>
__global__ __launch_bounds__(256) void agg_pull_wave(const float* __restrict__ feat_s,
                                                     const int* __restrict__ row_start,
                                                     const int* __restrict__ degI,
                                                     const int* __restrict__ src_sorted,
                                                     const float* __restrict__ dinv,
                                                     float* __restrict__ out, int n) {
    int node = __builtin_amdgcn_readfirstlane((int)(blockIdx.x * 4 + (threadIdx.x >> 6)));
    if (node >= n) return;
    const int lane = threadIdx.x & 63;
    int e = row_start[node];
    const int re = e + degI[node];
    const float di = dinv[node];

    if constexpr (VEC == 2) {
        const float2* __restrict__ f2 = (const float2*)feat_s;
        float2 acc = f2[(size_t)node * 64 + lane];   // self term (already dinv-scaled)
        for (; e + 3 < re; e += 4) {
            int s0 = src_sorted[e], s1 = src_sorted[e + 1],
                s2 = src_sorted[e + 2], s3 = src_sorted[e + 3];
            float2 a0 = f2[(size_t)s0 * 64 + lane];
            float2 a1 = f2[(size_t)s1 * 64 + lane];
            float2 a2 = f2[(size_t)s2 * 64 + lane];
            float2 a3 = f2[(size_t)s3 * 64 + lane];
            acc.x += (a0.x + a1.x) + (a2.x + a3.x);
            acc.y += (a0.y + a1.y) + (a2.y + a3.y);
        }
        for (; e < re; e++) {
            int s = src_sorted[e];
            float2 a = f2[(size_t)s * 64 + lane];
            acc.x += a.x;
            acc.y += a.y;
        }
        float2 o;
        o.x = acc.x * di;
        o.y = acc.y * di;
        ((float2*)out)[(size_t)node * 64 + lane] = o;
    } else {
        float acc = feat_s[(size_t)node * 64 + lane];
        for (; e + 3 < re; e += 4) {
            int s0 = src_sorted[e], s1 = src_sorted[e + 1],
                s2 = src_sorted[e + 2], s3 = src_sorted[e + 3];
            float a0 = feat_s[(size_t)s0 * 64 + lane];
            float a1 = feat_s[(size_t)s1 * 64 + lane];
            float a2 = feat_s[(size_t)s2 * 64 + lane];
            float a3 = feat_s[(size_t)s3 * 64 + lane];
            acc += (a0 + a1) + (a2 + a3);
        }
        for (; e < re; e++) {
            acc += feat_s[(size_t)src_sorted[e] * 64 + lane];
        }
        out[(size_t)node * 64 + lane] = acc * di;
    }
}

// ---------------------------------------------------------------------------
// GEMM (+ optional bias/BN/ReLU, + optional per-row dinv output scale)
template<int IN, int OUT, bool BNRELU, bool SCALEOUT>
__global__ __launch_bounds__(256) void gemm_bn(const float* __restrict__ in,
                                               const float* __restrict__ W,
                                               const float* __restrict__ bias,
                                               const float* __restrict__ gg,
                                               const float* __restrict__ bb,
                                               const float* __restrict__ mm,
                                               const float* __restrict__ vv,
                                               const float* __restrict__ dscale,
                                               float* __restrict__ out, int n) {
    constexpr int ROWS = 16;
    constexpr int RL = 256 / OUT;
    constexpr int RPT = ROWS / RL;
    __shared__ float s_in[ROWS][IN];
    const int r0 = blockIdx.x * ROWS;
    const int tid = threadIdx.x;

    for (int idx = tid; idx < ROWS * IN; idx += 256) {
        int rr = idx / IN, k = idx - rr * IN;
        int row = r0 + rr;
        s_in[rr][k] = (row < n) ? in[(size_t)row * IN + k] : 0.0f;
    }
    __syncthreads();

    const int c = tid % OUT;
    const int lr = tid / OUT;
    float acc[RPT];
#pragma unroll
    for (int j = 0; j < RPT; j++) acc[j] = 0.0f;

    for (int k = 0; k < IN; k++) {
        float w = W[k * OUT + c];
#pragma unroll
        for (int j = 0; j < RPT; j++) acc[j] += s_in[lr + j * RL][k] * w;
    }

    float scale = 1.0f, shift = 0.0f;
    if constexpr (BNRELU) {
        scale = gg[c] * rsqrtf(vv[c] + BN_EPS);
        shift = bb[c] + (bias[c] - mm[c]) * scale;
    }
#pragma unroll
    for (int j = 0; j < RPT; j++) {
        int row = r0 + lr + j * RL;
        if (row < n) {
            float val = acc[j];
            if constexpr (BNRELU) val = fmaxf(val * scale + shift, 0.0f);
            if constexpr (SCALEOUT) val *= dscale[row];
            out[(size_t)row * OUT + c] = val;
        }
    }
}

// ---------------------------------------------------------------------------
// per-graph node count
__global__ __launch_bounds__(256) void count_kernel(const int* __restrict__ batch,
                                                    float* __restrict__ cnt, int n) {
    int i = blockIdx.x * 256 + threadIdx.x;
    if (i < n) unsafeAtomicAdd(&cnt[batch[i]], 1.0f);
}

// layer-2 tail: h = relu(bn(aggB + b2)); pool[batch] += h   (64 ch)
__global__ __launch_bounds__(256) void final_node_kernel(const float* __restrict__ aggB,
                                                         const float* __restrict__ bias,
                                                         const float* __restrict__ gg,
                                                         const float* __restrict__ bb,
                                                         const float* __restrict__ mm,
                                                         const float* __restrict__ vv,
                                                         const int* __restrict__ batch,
                                                         float* __restrict__ pool, int n) {
    unsigned idx = blockIdx.x * 256u + threadIdx.x;
    if (idx >= (unsigned)n * 64u) return;
    unsigned i = idx >> 6, c = idx & 63u;
    float h = aggB[idx] + bias[c];
    float scale = gg[c] * rsqrtf(vv[c] + BN_EPS);
    float val = fmaxf((h - mm[c]) * scale + bb[c], 0.0f);
    unsafeAtomicAdd(&pool[(size_t)batch[i] * 64 + c], val);
}

// ---------------------------------------------------------------------------
// per-graph MLP head: 64 -> relu(128) -> relu(64) -> 2
__global__ __launch_bounds__(128) void fc_head_kernel(const float* __restrict__ pool,
                                                      const float* __restrict__ cnt,
                                                      const float* __restrict__ fw0,
                                                      const float* __restrict__ fb0,
                                                      const float* __restrict__ fw1,
                                                      const float* __restrict__ fb1,
                                                      const float* __restrict__ ow,
                                                      const float* __restrict__ ob,
                                                      float* __restrict__ out) {
    int g = blockIdx.x, tid = threadIdx.x;
    __shared__ float p[64], h1[128], h2[64];
    if (tid < 64) p[tid] = pool[g * 64 + tid] / fmaxf(cnt[g], 1.0f);
    __syncthreads();
    {
        float acc = fb0[tid];
        for (int k = 0; k < 64; k++) acc += p[k] * fw0[k * 128 + tid];
        h1[tid] = fmaxf(acc, 0.0f);
    }
    __syncthreads();
    if (tid < 64) {
        float acc = fb1[tid];
        for (int k = 0; k < 128; k++) acc += h1[k] * fw1[k * 64 + tid];
        h2[tid] = fmaxf(acc, 0.0f);
    }
    __syncthreads();
    if (tid < 2) {
        float acc = ob[tid];
        for (int k = 0; k < 64; k++) acc += h2[k] * ow[k * 2 + tid];
        out[g * 2 + tid] = acc;
    }
}

// ---------------------------------------------------------------------------
extern "C" void kernel_launch(void* const* d_in, const int* in_sizes, int n_in,
                              void* d_out, int out_size, void* d_ws, size_t ws_size,
                              hipStream_t stream) {
    const float* x     = (const float*)d_in[0];
    const int*   eidx  = (const int*)d_in[1];
    const int*   batch = (const int*)d_in[2];
    const float* w0 = (const float*)d_in[4];
    const float* b0 = (const float*)d_in[5];
    const float* g0 = (const float*)d_in[6];
    const float* be0 = (const float*)d_in[7];
    const float* m0 = (const float*)d_in[8];
    const float* v0 = (const float*)d_in[9];
    const float* w1 = (const float*)d_in[10];
    const float* b1 = (const float*)d_in[11];
    const float* g1 = (const float*)d_in[12];
    const float* be1 = (const float*)d_in[13];
    const float* m1 = (const float*)d_in[14];
    const float* v1 = (const float*)d_in[15];
    const float* w2 = (const float*)d_in[16];
    const float* b2 = (const float*)d_in[17];
    const float* g2 = (const float*)d_in[18];
    const float* be2 = (const float*)d_in[19];
    const float* m2 = (const float*)d_in[20];
    const float* v2 = (const float*)d_in[21];
    const float* fw0 = (const float*)d_in[22];
    const float* fb0 = (const float*)d_in[23];
    const float* fw1 = (const float*)d_in[24];
    const float* fb1 = (const float*)d_in[25];
    const float* ow = (const float*)d_in[26];
    const float* ob = (const float*)d_in[27];

    const int N = in_sizes[0] / 36;
    const int E = in_sizes[1] / 2;
    const int G = out_size / 2;
    const int* src = eidx;
    const int* dst = eidx + E;

    const int NB = (N + 255) / 256;   // scan blocks (must be <= 512)

    // ---- workspace layout
    char* wsb = (char*)d_ws;
    int*   degI       = (int*)wsb;                       wsb += (size_t)N * 4;
    int*   row_start  = (int*)wsb;                       wsb += (size_t)N * 4;
    int*   cursor     = (int*)wsb;                       wsb += (size_t)N * 4;
    int*   bsum       = (int*)wsb;                       wsb += 512 * 4;
    int*   src_sorted = (int*)wsb;                       wsb += (size_t)E * 4;
    float* dinv       = (float*)wsb;                     wsb += (size_t)N * 4;
    float* A          = (float*)wsb;                     wsb += (size_t)N * 128 * 4;
    float* B          = (float*)wsb;                     wsb += (size_t)N * 128 * 4;
    float* pool       = (float*)wsb;                     wsb += (size_t)G * 64 * 4;
    float* cnt        = (float*)wsb;

    // ---- degree, dinv, CSR
    hipMemsetAsync(degI, 0, (size_t)N * 4, stream);
    hipMemsetAsync(cursor, 0, (size_t)N * 4, stream);
    deg_count_kernel<<<(E + 255) / 256, 256, 0, stream>>>(dst, degI, E);
    dinv_kernel<<<NB, 256, 0, stream>>>(degI, dinv, N);
    scan_block<<<NB, 256, 0, stream>>>(degI, row_start, bsum, N);
    scan_bsum<<<1, 512, 0, stream>>>(bsum, NB);
    scan_add<<<NB, 256, 0, stream>>>(row_start, bsum, N);
    fill_csr<<<(E + 255) / 256, 256, 0, stream>>>(src, dst, row_start, cursor, src_sorted, E);

    const int NW = (N + 3) / 4;   // wave-per-node grid (4 waves/block)

    // ---- layer 0: pull 36-ch (x -> A), GEMM 36->128 +BN+ReLU, output scaled by dinv (A -> B)
    {
        unsigned total = (unsigned)N * 36u;
        agg_pull36<<<(total + 255) / 256, 256, 0, stream>>>(x, row_start, degI, src_sorted, dinv, A, N);
    }
    gemm_bn<36, 128, true, true><<<(N + 15) / 16, 256, 0, stream>>>(A, w0, b0, g0, be0, m0, v0, dinv, B, N);

    // ---- layer 1: pull 128-ch scaled (B -> A), GEMM 128->128 +BN+ReLU unscaled (A -> B)
    agg_pull_wave<2><<<NW, 256, 0, stream>>>(B, row_start, degI, src_sorted, dinv, A, N);
    gemm_bn<128, 128, true, false><<<(N + 15) / 16, 256, 0, stream>>>(A, w1, b1, g1, be1, m1, v1, nullptr, B, N);

    // ---- layer 2: GEMM 128->64 raw, output scaled (B -> A); pull 64-ch (A -> B)
    gemm_bn<128, 64, false, true><<<(N + 15) / 16, 256, 0, stream>>>(B, w2, nullptr, nullptr, nullptr, nullptr, nullptr, dinv, A, N);
    agg_pull_wave<1><<<NW, 256, 0, stream>>>(A, row_start, degI, src_sorted, dinv, B, N);

    // ---- pool (mean over batch) with fused bias+BN+ReLU
    hipMemsetAsync(pool, 0, (size_t)G * 64 * 4, stream);
    hipMemsetAsync(cnt, 0, (size_t)G * 4, stream);
    count_kernel<<<NB, 256, 0, stream>>>(batch, cnt, N);
    {
        unsigned total = (unsigned)N * 64u;
        final_node_kernel<<<(total + 255) / 256, 256, 0, stream>>>(B, b2, g2, be2, m2, v2, batch, pool, N);
    }

    // ---- MLP head
    fc_head_kernel<<<G, 128, 0, stream>>>(pool, cnt, fw0, fb0, fw1, fb1, ow, ob, (float*)d_out);
}

// Round 4
// 1091.486 us; speedup vs baseline: 2.8856x; 1.0387x over previous
//
#include <hip/hip_runtime.h>
#include <hip/hip_bf16.h>

#define BN_EPS 1e-5f

// ---------------------------------------------------------------------------
// degree count (int atomics)
__global__ __launch_bounds__(256) void deg_count_kernel(const int* __restrict__ dst,
                                                        int* __restrict__ degI, int nE) {
    int i = blockIdx.x * 256 + threadIdx.x;
    if (i < nE) atomicAdd(&degI[dst[i]], 1);
}

// dinv[i] = rsqrt(deg[i]+1); also zero the CSR fill cursor
__global__ __launch_bounds__(256) void dinv_kernel(const int* __restrict__ degI,
                                                   float* __restrict__ dinv,
                                                   int* __restrict__ cursor, int n) {
    int i = blockIdx.x * 256 + threadIdx.x;
    if (i < n) {
        dinv[i] = rsqrtf((float)degI[i] + 1.0f);
        cursor[i] = 0;
    }
}

// ---------------------------------------------------------------------------
// exclusive scan of degI -> row_start (3 phases)
__global__ __launch_bounds__(256) void scan_block(const int* __restrict__ degI,
                                                  int* __restrict__ ex,
                                                  int* __restrict__ bsum, int n) {
    __shared__ int tmp[256];
    int tid = threadIdx.x;
    int i = blockIdx.x * 256 + tid;
    int v = (i < n) ? degI[i] : 0;
    tmp[tid] = v;
    __syncthreads();
    for (int off = 1; off < 256; off <<= 1) {
        int t = (tid >= off) ? tmp[tid - off] : 0;
        __syncthreads();
        tmp[tid] += t;
        __syncthreads();
    }
    if (i < n) ex[i] = tmp[tid] - v;
    if (tid == 255) bsum[blockIdx.x] = tmp[255];
}

__global__ __launch_bounds__(512) void scan_bsum(int* __restrict__ bsum, int nb) {
    __shared__ int tmp[512];
    int tid = threadIdx.x;
    int v = (tid < nb) ? bsum[tid] : 0;
    tmp[tid] = v;
    __syncthreads();
    for (int off = 1; off < 512; off <<= 1) {
        int t = (tid >= off) ? tmp[tid - off] : 0;
        __syncthreads();
        tmp[tid] += t;
        __syncthreads();
    }
    if (tid < nb) bsum[tid] = tmp[tid] - v;
}

__global__ __launch_bounds__(256) void scan_add(int* __restrict__ ex,
                                                const int* __restrict__ bsum, int n) {
    int i = blockIdx.x * 256 + threadIdx.x;
    if (i < n) ex[i] += bsum[blockIdx.x];
}

// ---------------------------------------------------------------------------
// CSR fill: place each edge's src into its dst's segment
__global__ __launch_bounds__(256) void fill_csr(const int* __restrict__ src,
                                                const int* __restrict__ dst,
                                                const int* __restrict__ row_start,
                                                int* __restrict__ cursor,
                                                int* __restrict__ src_sorted, int nE) {
    int i = blockIdx.x * 256 + threadIdx.x;
    if (i < nE) {
        int d = dst[i];
        int pos = row_start[d] + atomicAdd(&cursor[d], 1);
        src_sorted[pos] = src[i];
    }
}

// ---------------------------------------------------------------------------
// xs[i,c] = x[i,c] * dinv[i]
__global__ __launch_bounds__(256) void prescale36(const float* __restrict__ x,
                                                  const float* __restrict__ dinv,
                                                  float* __restrict__ xs, int n) {
    unsigned idx = blockIdx.x * 256u + threadIdx.x;
    if (idx >= (unsigned)n * 36u) return;
    xs[idx] = x[idx] * dinv[idx / 36u];
}

// wave-per-node pull over pre-scaled 36-ch features:
//   out[i] = dinv_i * ( xs[i] + sum_{s in N(i)} xs[s] )
__global__ __launch_bounds__(256) void agg_pull36w(const float* __restrict__ xs,
                                                   const int* __restrict__ row_start,
                                                   const int* __restrict__ degI,
                                                   const int* __restrict__ src_sorted,
                                                   const float* __restrict__ dinv,
                                                   float* __restrict__ out, int n) {
    int node = __builtin_amdgcn_readfirstlane((int)(blockIdx.x * 4 + (threadIdx.x >> 6)));
    if (node >= n) return;
    const int lane = threadIdx.x & 63;
    int e = row_start[node];
    const int re = e + degI[node];
    const float di = dinv[node];
    float acc = 0.0f;
    if (lane < 36) acc = xs[(size_t)node * 36 + lane];
    for (; e + 3 < re; e += 4) {
        int s0 = src_sorted[e], s1 = src_sorted[e + 1],
            s2 = src_sorted[e + 2], s3 = src_sorted[e + 3];
        if (lane < 36) {
            float a0 = xs[(size_t)s0 * 36 + lane];
            float a1 = xs[(size_t)s1 * 36 + lane];
            float a2 = xs[(size_t)s2 * 36 + lane];
            float a3 = xs[(size_t)s3 * 36 + lane];
            acc += (a0 + a1) + (a2 + a3);
        }
    }
    for (; e < re; e++) {
        int s = src_sorted[e];
        if (lane < 36) acc += xs[(size_t)s * 36 + lane];
    }
    if (lane < 36) out[(size_t)node * 36 + lane] = acc * di;
}

// ---------------------------------------------------------------------------
// wave-per-node pull over PRE-SCALED features (feat_s = dinv .* h):
//   out[i] = dinv_i * ( feat_s[i] + sum_{s in N(i)} feat_s[s] )
// VEC=2 -> CH=128 (float2/lane), VEC=1 -> CH=64 (float/lane)
template<int VEC>
__global__ __launch_bounds__(256) void agg_pull_wave(const float* __restrict__ feat_s,
                                                     const int* __restrict__ row_start,
                                                     const int* __restrict__ degI,
                                                     const int* __restrict__ src_sorted,
                                                     const float* __restrict__ dinv,
                                                     float* __restrict__ out, int n) {
    int node = __builtin_amdgcn_readfirstlane((int)(blockIdx.x * 4 + (threadIdx.x >> 6)));
    if (node >= n) return;
    const int lane = threadIdx.x & 63;
    int e = row_start[node];
    const int re = e + degI[node];
    const float di = dinv[node];

    if constexpr (VEC == 2) {
        const float2* __restrict__ f2 = (const float2*)feat_s;
        float2 acc = f2[(size_t)node * 64 + lane];
        for (; e + 3 < re; e += 4) {
            int s0 = src_sorted[e], s1 = src_sorted[e + 1],
                s2 = src_sorted[e + 2], s3 = src_sorted[e + 3];
            float2 a0 = f2[(size_t)s0 * 64 + lane];
            float2 a1 = f2[(size_t)s1 * 64 + lane];
            float2 a2 = f2[(size_t)s2 * 64 + lane];
            float2 a3 = f2[(size_t)s3 * 64 + lane];
            acc.x += (a0.x + a1.x) + (a2.x + a3.x);
            acc.y += (a0.y + a1.y) + (a2.y + a3.y);
        }
        for (; e < re; e++) {
            int s = src_sorted[e];
            float2 a = f2[(size_t)s * 64 + lane];
            acc.x += a.x;
            acc.y += a.y;
        }
        float2 o;
        o.x = acc.x * di;
        o.y = acc.y * di;
        ((float2*)out)[(size_t)node * 64 + lane] = o;
    } else {
        float acc = feat_s[(size_t)node * 64 + lane];
        for (; e + 3 < re; e += 4) {
            int s0 = src_sorted[e], s1 = src_sorted[e + 1],
                s2 = src_sorted[e + 2], s3 = src_sorted[e + 3];
            float a0 = feat_s[(size_t)s0 * 64 + lane];
            float a1 = feat_s[(size_t)s1 * 64 + lane];
            float a2 = feat_s[(size_t)s2 * 64 + lane];
            float a3 = feat_s[(size_t)s3 * 64 + lane];
            acc += (a0 + a1) + (a2 + a3);
        }
        for (; e < re; e++) {
            acc += feat_s[(size_t)src_sorted[e] * 64 + lane];
        }
        out[(size_t)node * 64 + lane] = acc * di;
    }
}

// ---------------------------------------------------------------------------
// Register-tiled fp32 GEMM: 64-row tile in LDS, each thread computes TM x 8.
//   out = [BNRELU? relu(bn(in@W + bias))] [* SCALEOUT? dscale[row]]
template<int IN, int OUT, bool BNRELU, bool SCALEOUT>
__global__ __launch_bounds__(256) void gemm_rt(const float* __restrict__ in,
                                               const float* __restrict__ W,
                                               const float* __restrict__ bias,
                                               const float* __restrict__ gg,
                                               const float* __restrict__ bb,
                                               const float* __restrict__ mm,
                                               const float* __restrict__ vv,
                                               const float* __restrict__ dscale,
                                               float* __restrict__ out, int n) {
    constexpr int BM = 64;
    constexpr int TN = 8;
    constexpr int CG = OUT / TN;            // col groups: 16 (OUT=128) / 8 (OUT=64)
    constexpr int RG = 256 / CG;            // row groups: 16 / 32
    constexpr int TM = BM / RG;             // rows/thread: 4 / 2
    constexpr int PAD = (IN == 36) ? 8 : 4; // stride%4==0 and (TM*stride)%32==16 -> 2-way max
    constexpr int LDW = IN + PAD;
    __shared__ float s_a[BM][LDW];

    const int r0 = blockIdx.x * BM;
    const int tid = threadIdx.x;

    // coalesced row-major staging (float4); IN % 4 == 0 for 128, 64, 36
    constexpr int T4 = BM * IN / 4;
    for (int i4 = tid; i4 < T4; i4 += 256) {
        int idx = i4 * 4;
        int r = idx / IN;
        int k = idx - r * IN;
        int row = r0 + r;
        float4 v = make_float4(0.f, 0.f, 0.f, 0.f);
        if (row < n) v = *(const float4*)(in + (size_t)row * IN + k);
        *(float4*)&s_a[r][k] = v;
    }
    __syncthreads();

    const int tx = tid % CG;
    const int ty = tid / CG;
    const int c0 = tx * TN;
    const int rr = ty * TM;

    float acc[TM][TN];
#pragma unroll
    for (int j = 0; j < TM; j++)
#pragma unroll
        for (int t = 0; t < TN; t++) acc[j][t] = 0.0f;

#pragma unroll 2
    for (int k = 0; k < IN; k += 4) {
        float4 a[TM];
#pragma unroll
        for (int j = 0; j < TM; j++) a[j] = *(const float4*)&s_a[rr + j][k];
#pragma unroll
        for (int kk = 0; kk < 4; kk++) {
            float4 wv0 = *(const float4*)(W + (size_t)(k + kk) * OUT + c0);
            float4 wv1 = *(const float4*)(W + (size_t)(k + kk) * OUT + c0 + 4);
#pragma unroll
            for (int j = 0; j < TM; j++) {
                float av = (kk == 0) ? a[j].x : (kk == 1) ? a[j].y : (kk == 2) ? a[j].z : a[j].w;
                acc[j][0] += av * wv0.x;
                acc[j][1] += av * wv0.y;
                acc[j][2] += av * wv0.z;
                acc[j][3] += av * wv0.w;
                acc[j][4] += av * wv1.x;
                acc[j][5] += av * wv1.y;
                acc[j][6] += av * wv1.z;
                acc[j][7] += av * wv1.w;
            }
        }
    }

    float scl[TN], sft[TN];
    if constexpr (BNRELU) {
#pragma unroll
        for (int t = 0; t < TN; t++) {
            float s = gg[c0 + t] * rsqrtf(vv[c0 + t] + BN_EPS);
            scl[t] = s;
            sft[t] = bb[c0 + t] + (bias[c0 + t] - mm[c0 + t]) * s;
        }
    }

#pragma unroll
    for (int j = 0; j < TM; j++) {
        int row = r0 + rr + j;
        if (row < n) {
            float ds = 1.0f;
            if constexpr (SCALEOUT) ds = dscale[row];
            float o[TN];
#pragma unroll
            for (int t = 0; t < TN; t++) {
                float val = acc[j][t];
                if constexpr (BNRELU) val = fmaxf(val * scl[t] + sft[t], 0.0f);
                if constexpr (SCALEOUT) val *= ds;
                o[t] = val;
            }
            float* op = out + (size_t)row * OUT + c0;
            *(float4*)op = make_float4(o[0], o[1], o[2], o[3]);
            *(float4*)(op + 4) = make_float4(o[4], o[5], o[6], o[7]);
        }
    }
}

// ---------------------------------------------------------------------------
// per-graph node count
__global__ __launch_bounds__(256) void count_kernel(const int* __restrict__ batch,
                                                    float* __restrict__ cnt, int n) {
    int i = blockIdx.x * 256 + threadIdx.x;
    if (i < n) unsafeAtomicAdd(&cnt[batch[i]], 1.0f);
}

// layer-2 tail: h = relu(bn(aggB + b2)); pool[batch] += h   (64 ch)
__global__ __launch_bounds__(256) void final_node_kernel(const float* __restrict__ aggB,
                                                         const float* __restrict__ bias,
                                                         const float* __restrict__ gg,
                                                         const float* __restrict__ bb,
                                                         const float* __restrict__ mm,
                                                         const float* __restrict__ vv,
                                                         const int* __restrict__ batch,
                                                         float* __restrict__ pool, int n) {
    unsigned idx = blockIdx.x * 256u + threadIdx.x;
    if (idx >= (unsigned)n * 64u) return;
    unsigned i = idx >> 6, c = idx & 63u;
    float h = aggB[idx] + bias[c];
    float scale = gg[c] * rsqrtf(vv[c] + BN_EPS);
    float val = fmaxf((h - mm[c]) * scale + bb[c], 0.0f);
    unsafeAtomicAdd(&pool[(size_t)batch[i] * 64 + c], val);
}

// ---------------------------------------------------------------------------
// per-graph MLP head: 64 -> relu(128) -> relu(64) -> 2
__global__ __launch_bounds__(128) void fc_head_kernel(const float* __restrict__ pool,
                                                      const float* __restrict__ cnt,
                                                      const float* __restrict__ fw0,
                                                      const float* __restrict__ fb0,
                                                      const float* __restrict__ fw1,
                                                      const float* __restrict__ fb1,
                                                      const float* __restrict__ ow,
                                                      const float* __restrict__ ob,
                                                      float* __restrict__ out) {
    int g = blockIdx.x, tid = threadIdx.x;
    __shared__ float p[64], h1[128], h2[64];
    if (tid < 64) p[tid] = pool[g * 64 + tid] / fmaxf(cnt[g], 1.0f);
    __syncthreads();
    {
        float acc = fb0[tid];
        for (int k = 0; k < 64; k++) acc += p[k] * fw0[k * 128 + tid];
        h1[tid] = fmaxf(acc, 0.0f);
    }
    __syncthreads();
    if (tid < 64) {
        float acc = fb1[tid];
        for (int k = 0; k < 128; k++) acc += h1[k] * fw1[k * 64 + tid];
        h2[tid] = fmaxf(acc, 0.0f);
    }
    __syncthreads();
    if (tid < 2) {
        float acc = ob[tid];
        for (int k = 0; k < 64; k++) acc += h2[k] * ow[k * 2 + tid];
        out[g * 2 + tid] = acc;
    }
}

// ---------------------------------------------------------------------------
extern "C" void kernel_launch(void* const* d_in, const int* in_sizes, int n_in,
                              void* d_out, int out_size, void* d_ws, size_t ws_size,
                              hipStream_t stream) {
    const float* x     = (const float*)d_in[0];
    const int*   eidx  = (const int*)d_in[1];
    const int*   batch = (const int*)d_in[2];
    const float* w0 = (const float*)d_in[4];
    const float* b0 = (const float*)d_in[5];
    const float* g0 = (const float*)d_in[6];
    const float* be0 = (const float*)d_in[7];
    const float* m0 = (const float*)d_in[8];
    const float* v0 = (const float*)d_in[9];
    const float* w1 = (const float*)d_in[10];
    const float* b1 = (const float*)d_in[11];
    const float* g1 = (const float*)d_in[12];
    const float* be1 = (const float*)d_in[13];
    const float* m1 = (const float*)d_in[14];
    const float* v1 = (const float*)d_in[15];
    const float* w2 = (const float*)d_in[16];
    const float* b2 = (const float*)d_in[17];
    const float* g2 = (const float*)d_in[18];
    const float* be2 = (const float*)d_in[19];
    const float* m2 = (const float*)d_in[20];
    const float* v2 = (const float*)d_in[21];
    const float* fw0 = (const float*)d_in[22];
    const float* fb0 = (const float*)d_in[23];
    const float* fw1 = (const float*)d_in[24];
    const float* fb1 = (const float*)d_in[25];
    const float* ow = (const float*)d_in[26];
    const float* ob = (const float*)d_in[27];

    const int N = in_sizes[0] / 36;
    const int E = in_sizes[1] / 2;
    const int G = out_size / 2;
    const int* src = eidx;
    const int* dst = eidx + E;

    const int NB = (N + 255) / 256;   // scan blocks (must be <= 512)

    // ---- workspace layout
    char* wsb = (char*)d_ws;
    int*   degI       = (int*)wsb;                       wsb += (size_t)N * 4;
    int*   row_start  = (int*)wsb;                       wsb += (size_t)N * 4;
    int*   cursor     = (int*)wsb;                       wsb += (size_t)N * 4;
    int*   bsum       = (int*)wsb;                       wsb += 512 * 4;
    int*   src_sorted = (int*)wsb;                       wsb += (size_t)E * 4;
    float* dinv       = (float*)wsb;                     wsb += (size_t)N * 4;
    float* A          = (float*)wsb;                     wsb += (size_t)N * 128 * 4;
    float* B          = (float*)wsb;                     wsb += (size_t)N * 128 * 4;
    float* pool       = (float*)wsb;                     wsb += (size_t)G * 64 * 4;
    float* cnt        = (float*)wsb;

    // ---- degree, dinv, CSR
    hipMemsetAsync(degI, 0, (size_t)N * 4, stream);
    deg_count_kernel<<<(E + 255) / 256, 256, 0, stream>>>(dst, degI, E);
    dinv_kernel<<<NB, 256, 0, stream>>>(degI, dinv, cursor, N);
    scan_block<<<NB, 256, 0, stream>>>(degI, row_start, bsum, N);
    scan_bsum<<<1, 512, 0, stream>>>(bsum, NB);
    scan_add<<<NB, 256, 0, stream>>>(row_start, bsum, N);
    fill_csr<<<(E + 255) / 256, 256, 0, stream>>>(src, dst, row_start, cursor, src_sorted, E);

    const int NW = (N + 3) / 4;     // wave-per-node grid (4 waves/block)
    const int NG = (N + 63) / 64;   // gemm grid (64 rows/block)

    // ---- layer 0: xs = dinv.*x (stored in B), pull 36-ch (B -> A),
    //      GEMM 36->128 +BN+ReLU, output scaled by dinv (A -> B)
    {
        unsigned total = (unsigned)N * 36u;
        prescale36<<<(total + 255) / 256, 256, 0, stream>>>(x, dinv, B, N);
    }
    agg_pull36w<<<NW, 256, 0, stream>>>(B, row_start, degI, src_sorted, dinv, A, N);
    gemm_rt<36, 128, true, true><<<NG, 256, 0, stream>>>(A, w0, b0, g0, be0, m0, v0, dinv, B, N);

    // ---- layer 1: pull 128-ch scaled (B -> A), GEMM 128->128 +BN+ReLU unscaled (A -> B)
    agg_pull_wave<2><<<NW, 256, 0, stream>>>(B, row_start, degI, src_sorted, dinv, A, N);
    gemm_rt<128, 128, true, false><<<NG, 256, 0, stream>>>(A, w1, b1, g1, be1, m1, v1, nullptr, B, N);

    // ---- layer 2: GEMM 128->64 raw, output scaled (B -> A); pull 64-ch (A -> B)
    gemm_rt<128, 64, false, true><<<NG, 256, 0, stream>>>(B, w2, nullptr, nullptr, nullptr, nullptr, nullptr, dinv, A, N);
    agg_pull_wave<1><<<NW, 256, 0, stream>>>(A, row_start, degI, src_sorted, dinv, B, N);

    // ---- pool (mean over batch) with fused bias+BN+ReLU
    hipMemsetAsync(pool, 0, (size_t)G * 64 * 4, stream);
    hipMemsetAsync(cnt, 0, (size_t)G * 4, stream);
    count_kernel<<<NB, 256, 0, stream>>>(batch, cnt, N);
    {
        unsigned total = (unsigned)N * 64u;
        final_node_kernel<<<(total + 255) / 256, 256, 0, stream>>>(B, b2, g2, be2, m2, v2, batch, pool, N);
    }

    // ---- MLP head
    fc_head_kernel<<<G, 128, 0, stream>>>(pool, cnt, fw0, fb0, fw1, fb1, ow, ob, (float*)d_out);
}

// Round 5
// 857.548 us; speedup vs baseline: 3.6727x; 1.2728x over previous
//
#include <hip/hip_runtime.h>
#include <hip/hip_bf16.h>

#define BN_EPS 1e-5f

// Buckets of 512 nodes: bucket = dst >> 9. N=100K -> 196 buckets (<=256).
#define BUCK_SHIFT 9
#define NBUCK_MAX 256
#define PBLK 512   // blocks for hist/scatter passes

// ---------------------------------------------------------------------------
// dinv[i] = rsqrt(deg[i]+1)
__global__ __launch_bounds__(256) void dinv_kernel(const int* __restrict__ degI,
                                                   float* __restrict__ dinv, int n) {
    int i = blockIdx.x * 256 + threadIdx.x;
    if (i < n) dinv[i] = rsqrtf((float)degI[i] + 1.0f);
}

// ---------------------------------------------------------------------------
// generic exclusive scan (3 phases), n <= 512*256
__global__ __launch_bounds__(256) void scan_block(const int* __restrict__ in,
                                                  int* __restrict__ ex,
                                                  int* __restrict__ bsum, int n) {
    __shared__ int tmp[256];
    int tid = threadIdx.x;
    int i = blockIdx.x * 256 + tid;
    int v = (i < n) ? in[i] : 0;
    tmp[tid] = v;
    __syncthreads();
    for (int off = 1; off < 256; off <<= 1) {
        int t = (tid >= off) ? tmp[tid - off] : 0;
        __syncthreads();
        tmp[tid] += t;
        __syncthreads();
    }
    if (i < n) ex[i] = tmp[tid] - v;
    if (tid == 255) bsum[blockIdx.x] = tmp[255];
}

__global__ __launch_bounds__(512) void scan_bsum(int* __restrict__ bsum, int nb) {
    __shared__ int tmp[512];
    int tid = threadIdx.x;
    int v = (tid < nb) ? bsum[tid] : 0;
    tmp[tid] = v;
    __syncthreads();
    for (int off = 1; off < 512; off <<= 1) {
        int t = (tid >= off) ? tmp[tid - off] : 0;
        __syncthreads();
        tmp[tid] += t;
        __syncthreads();
    }
    if (tid < nb) bsum[tid] = tmp[tid] - v;
}

__global__ __launch_bounds__(256) void scan_add(int* __restrict__ ex,
                                                const int* __restrict__ bsum, int n) {
    int i = blockIdx.x * 256 + threadIdx.x;
    if (i < n) ex[i] += bsum[blockIdx.x];
}

// ---------------------------------------------------------------------------
// Phase A: per-block bucket histogram -> counts[bucket*P + blk]
__global__ __launch_bounds__(256) void bucket_hist(const int* __restrict__ dst,
                                                   int* __restrict__ counts,
                                                   int nE, int nbuck, int chunk) {
    __shared__ int h[NBUCK_MAX];
    const int blk = blockIdx.x, tid = threadIdx.x;
    for (int j = tid; j < nbuck; j += 256) h[j] = 0;
    __syncthreads();
    const int base = blk * chunk;
    const int end = min(base + chunk, nE);
    for (int i = base + tid; i < end; i += 256)
        atomicAdd(&h[dst[i] >> BUCK_SHIFT], 1);
    __syncthreads();
    for (int j = tid; j < nbuck; j += 256)
        counts[j * PBLK + blk] = h[j];
}

// Phase C: scatter edges into bucket-grouped ebuf using scanned offsets
__global__ __launch_bounds__(256) void bucket_scatter(const int* __restrict__ src,
                                                      const int* __restrict__ dst,
                                                      const int* __restrict__ offs,
                                                      int2* __restrict__ ebuf,
                                                      int nE, int nbuck, int chunk) {
    __shared__ int cur[NBUCK_MAX];
    const int blk = blockIdx.x, tid = threadIdx.x;
    for (int j = tid; j < nbuck; j += 256) cur[j] = offs[j * PBLK + blk];
    __syncthreads();
    const int base = blk * chunk;
    const int end = min(base + chunk, nE);
    for (int i = base + tid; i < end; i += 256) {
        int d = dst[i];
        int pos = atomicAdd(&cur[d >> BUCK_SHIFT], 1);
        ebuf[pos] = make_int2(src[i], d);
    }
}

// Phase D1: per-node degree via LDS histogram (one block per bucket)
__global__ __launch_bounds__(256) void bucket_degree(const int2* __restrict__ ebuf,
                                                     const int* __restrict__ offs,
                                                     int* __restrict__ degI,
                                                     int nE, int nbuck, int n) {
    __shared__ int deg[512];
    const int b = blockIdx.x, tid = threadIdx.x;
    const int base = b << BUCK_SHIFT;
    for (int j = tid; j < 512; j += 256) deg[j] = 0;
    __syncthreads();
    const int s = offs[b * PBLK];
    const int e = (b + 1 < nbuck) ? offs[(b + 1) * PBLK] : nE;
    for (int i = s + tid; i < e; i += 256)
        atomicAdd(&deg[ebuf[i].y - base], 1);
    __syncthreads();
    for (int j = tid; j < 512; j += 256)
        if (base + j < n) degI[base + j] = deg[j];
}

// Phase D2: fine CSR fill with LDS cursors (one block per bucket)
__global__ __launch_bounds__(256) void bucket_fill(const int2* __restrict__ ebuf,
                                                   const int* __restrict__ offs,
                                                   const int* __restrict__ row_start,
                                                   int* __restrict__ src_sorted,
                                                   int nE, int nbuck, int n) {
    __shared__ int cur[512];
    const int b = blockIdx.x, tid = threadIdx.x;
    const int base = b << BUCK_SHIFT;
    for (int j = tid; j < 512; j += 256) {
        int node = base + j;
        cur[j] = (node < n) ? row_start[node] : 0;
    }
    __syncthreads();
    const int s = offs[b * PBLK];
    const int e = (b + 1 < nbuck) ? offs[(b + 1) * PBLK] : nE;
    for (int i = s + tid; i < e; i += 256) {
        int2 ed = ebuf[i];
        int pos = atomicAdd(&cur[ed.y - base], 1);
        src_sorted[pos] = ed.x;
    }
}

// ---------------------------------------------------------------------------
// xs[i,c] = x[i,c] * dinv[i]
__global__ __launch_bounds__(256) void prescale36(const float* __restrict__ x,
                                                  const float* __restrict__ dinv,
                                                  float* __restrict__ xs, int n) {
    unsigned idx = blockIdx.x * 256u + threadIdx.x;
    if (idx >= (unsigned)n * 36u) return;
    xs[idx] = x[idx] * dinv[idx / 36u];
}

// wave-per-node pull over pre-scaled 36-ch features
__global__ __launch_bounds__(256) void agg_pull36w(const float* __restrict__ xs,
                                                   const int* __restrict__ row_start,
                                                   const int* __restrict__ degI,
                                                   const int* __restrict__ src_sorted,
                                                   const float* __restrict__ dinv,
                                                   float* __restrict__ out, int n) {
    int node = __builtin_amdgcn_readfirstlane((int)(blockIdx.x * 4 + (threadIdx.x >> 6)));
    if (node >= n) return;
    const int lane = threadIdx.x & 63;
    int e = row_start[node];
    const int re = e + degI[node];
    const float di = dinv[node];
    float acc = 0.0f;
    if (lane < 36) acc = xs[(size_t)node * 36 + lane];
    for (; e + 3 < re; e += 4) {
        int s0 = src_sorted[e], s1 = src_sorted[e + 1],
            s2 = src_sorted[e + 2], s3 = src_sorted[e + 3];
        if (lane < 36) {
            float a0 = xs[(size_t)s0 * 36 + lane];
            float a1 = xs[(size_t)s1 * 36 + lane];
            float a2 = xs[(size_t)s2 * 36 + lane];
            float a3 = xs[(size_t)s3 * 36 + lane];
            acc += (a0 + a1) + (a2 + a3);
        }
    }
    for (; e < re; e++) {
        int s = src_sorted[e];
        if (lane < 36) acc += xs[(size_t)s * 36 + lane];
    }
    if (lane < 36) out[(size_t)node * 36 + lane] = acc * di;
}

// ---------------------------------------------------------------------------
// wave-per-node pull over PRE-SCALED features; VEC=2 -> 128ch, VEC=1 -> 64ch
template<int VEC>
__global__ __launch_bounds__(256) void agg_pull_wave(const float* __restrict__ feat_s,
                                                     const int* __restrict__ row_start,
                                                     const int* __restrict__ degI,
                                                     const int* __restrict__ src_sorted,
                                                     const float* __restrict__ dinv,
                                                     float* __restrict__ out, int n) {
    int node = __builtin_amdgcn_readfirstlane((int)(blockIdx.x * 4 + (threadIdx.x >> 6)));
    if (node >= n) return;
    const int lane = threadIdx.x & 63;
    int e = row_start[node];
    const int re = e + degI[node];
    const float di = dinv[node];

    if constexpr (VEC == 2) {
        const float2* __restrict__ f2 = (const float2*)feat_s;
        float2 acc = f2[(size_t)node * 64 + lane];
        for (; e + 3 < re; e += 4) {
            int s0 = src_sorted[e], s1 = src_sorted[e + 1],
                s2 = src_sorted[e + 2], s3 = src_sorted[e + 3];
            float2 a0 = f2[(size_t)s0 * 64 + lane];
            float2 a1 = f2[(size_t)s1 * 64 + lane];
            float2 a2 = f2[(size_t)s2 * 64 + lane];
            float2 a3 = f2[(size_t)s3 * 64 + lane];
            acc.x += (a0.x + a1.x) + (a2.x + a3.x);
            acc.y += (a0.y + a1.y) + (a2.y + a3.y);
        }
        for (; e < re; e++) {
            int s = src_sorted[e];
            float2 a = f2[(size_t)s * 64 + lane];
            acc.x += a.x;
            acc.y += a.y;
        }
        float2 o;
        o.x = acc.x * di;
        o.y = acc.y * di;
        ((float2*)out)[(size_t)node * 64 + lane] = o;
    } else {
        float acc = feat_s[(size_t)node * 64 + lane];
        for (; e + 3 < re; e += 4) {
            int s0 = src_sorted[e], s1 = src_sorted[e + 1],
                s2 = src_sorted[e + 2], s3 = src_sorted[e + 3];
            float a0 = feat_s[(size_t)s0 * 64 + lane];
            float a1 = feat_s[(size_t)s1 * 64 + lane];
            float a2 = feat_s[(size_t)s2 * 64 + lane];
            float a3 = feat_s[(size_t)s3 * 64 + lane];
            acc += (a0 + a1) + (a2 + a3);
        }
        for (; e < re; e++) {
            acc += feat_s[(size_t)src_sorted[e] * 64 + lane];
        }
        out[(size_t)node * 64 + lane] = acc * di;
    }
}

// ---------------------------------------------------------------------------
// Register-tiled fp32 GEMM: 64-row tile in LDS, each thread computes TM x 8.
template<int IN, int OUT, bool BNRELU, bool SCALEOUT>
__global__ __launch_bounds__(256) void gemm_rt(const float* __restrict__ in,
                                               const float* __restrict__ W,
                                               const float* __restrict__ bias,
                                               const float* __restrict__ gg,
                                               const float* __restrict__ bb,
                                               const float* __restrict__ mm,
                                               const float* __restrict__ vv,
                                               const float* __restrict__ dscale,
                                               float* __restrict__ out, int n) {
    constexpr int BM = 64;
    constexpr int TN = 8;
    constexpr int CG = OUT / TN;
    constexpr int RG = 256 / CG;
    constexpr int TM = BM / RG;
    constexpr int PAD = (IN == 36) ? 8 : 4;
    constexpr int LDW = IN + PAD;
    __shared__ float s_a[BM][LDW];

    const int r0 = blockIdx.x * BM;
    const int tid = threadIdx.x;

    constexpr int T4 = BM * IN / 4;
    for (int i4 = tid; i4 < T4; i4 += 256) {
        int idx = i4 * 4;
        int r = idx / IN;
        int k = idx - r * IN;
        int row = r0 + r;
        float4 v = make_float4(0.f, 0.f, 0.f, 0.f);
        if (row < n) v = *(const float4*)(in + (size_t)row * IN + k);
        *(float4*)&s_a[r][k] = v;
    }
    __syncthreads();

    const int tx = tid % CG;
    const int ty = tid / CG;
    const int c0 = tx * TN;
    const int rr = ty * TM;

    float acc[TM][TN];
#pragma unroll
    for (int j = 0; j < TM; j++)
#pragma unroll
        for (int t = 0; t < TN; t++) acc[j][t] = 0.0f;

#pragma unroll 2
    for (int k = 0; k < IN; k += 4) {
        float4 a[TM];
#pragma unroll
        for (int j = 0; j < TM; j++) a[j] = *(const float4*)&s_a[rr + j][k];
#pragma unroll
        for (int kk = 0; kk < 4; kk++) {
            float4 wv0 = *(const float4*)(W + (size_t)(k + kk) * OUT + c0);
            float4 wv1 = *(const float4*)(W + (size_t)(k + kk) * OUT + c0 + 4);
#pragma unroll
            for (int j = 0; j < TM; j++) {
                float av = (kk == 0) ? a[j].x : (kk == 1) ? a[j].y : (kk == 2) ? a[j].z : a[j].w;
                acc[j][0] += av * wv0.x;
                acc[j][1] += av * wv0.y;
                acc[j][2] += av * wv0.z;
                acc[j][3] += av * wv0.w;
                acc[j][4] += av * wv1.x;
                acc[j][5] += av * wv1.y;
                acc[j][6] += av * wv1.z;
                acc[j][7] += av * wv1.w;
            }
        }
    }

    float scl[TN], sft[TN];
    if constexpr (BNRELU) {
#pragma unroll
        for (int t = 0; t < TN; t++) {
            float s = gg[c0 + t] * rsqrtf(vv[c0 + t] + BN_EPS);
            scl[t] = s;
            sft[t] = bb[c0 + t] + (bias[c0 + t] - mm[c0 + t]) * s;
        }
    }

#pragma unroll
    for (int j = 0; j < TM; j++) {
        int row = r0 + rr + j;
        if (row < n) {
            float ds = 1.0f;
            if constexpr (SCALEOUT) ds = dscale[row];
            float o[TN];
#pragma unroll
            for (int t = 0; t < TN; t++) {
                float val = acc[j][t];
                if constexpr (BNRELU) val = fmaxf(val * scl[t] + sft[t], 0.0f);
                if constexpr (SCALEOUT) val *= ds;
                o[t] = val;
            }
            float* op = out + (size_t)row * OUT + c0;
            *(float4*)op = make_float4(o[0], o[1], o[2], o[3]);
            *(float4*)(op + 4) = make_float4(o[4], o[5], o[6], o[7]);
        }
    }
}

// ---------------------------------------------------------------------------
// per-graph node count
__global__ __launch_bounds__(256) void count_kernel(const int* __restrict__ batch,
                                                    float* __restrict__ cnt, int n) {
    int i = blockIdx.x * 256 + threadIdx.x;
    if (i < n) unsafeAtomicAdd(&cnt[batch[i]], 1.0f);
}

// layer-2 tail: h = relu(bn(aggB + b2)); pool[batch] += h   (64 ch)
__global__ __launch_bounds__(256) void final_node_kernel(const float* __restrict__ aggB,
                                                         const float* __restrict__ bias,
                                                         const float* __restrict__ gg,
                                                         const float* __restrict__ bb,
                                                         const float* __restrict__ mm,
                                                         const float* __restrict__ vv,
                                                         const int* __restrict__ batch,
                                                         float* __restrict__ pool, int n) {
    unsigned idx = blockIdx.x * 256u + threadIdx.x;
    if (idx >= (unsigned)n * 64u) return;
    unsigned i = idx >> 6, c = idx & 63u;
    float h = aggB[idx] + bias[c];
    float scale = gg[c] * rsqrtf(vv[c] + BN_EPS);
    float val = fmaxf((h - mm[c]) * scale + bb[c], 0.0f);
    unsafeAtomicAdd(&pool[(size_t)batch[i] * 64 + c], val);
}

// ---------------------------------------------------------------------------
// per-graph MLP head: 64 -> relu(128) -> relu(64) -> 2
__global__ __launch_bounds__(128) void fc_head_kernel(const float* __restrict__ pool,
                                                      const float* __restrict__ cnt,
                                                      const float* __restrict__ fw0,
                                                      const float* __restrict__ fb0,
                                                      const float* __restrict__ fw1,
                                                      const float* __restrict__ fb1,
                                                      const float* __restrict__ ow,
                                                      const float* __restrict__ ob,
                                                      float* __restrict__ out) {
    int g = blockIdx.x, tid = threadIdx.x;
    __shared__ float p[64], h1[128], h2[64];
    if (tid < 64) p[tid] = pool[g * 64 + tid] / fmaxf(cnt[g], 1.0f);
    __syncthreads();
    {
        float acc = fb0[tid];
        for (int k = 0; k < 64; k++) acc += p[k] * fw0[k * 128 + tid];
        h1[tid] = fmaxf(acc, 0.0f);
    }
    __syncthreads();
    if (tid < 64) {
        float acc = fb1[tid];
        for (int k = 0; k < 128; k++) acc += h1[k] * fw1[k * 64 + tid];
        h2[tid] = fmaxf(acc, 0.0f);
    }
    __syncthreads();
    if (tid < 2) {
        float acc = ob[tid];
        for (int k = 0; k < 64; k++) acc += h2[k] * ow[k * 2 + tid];
        out[g * 2 + tid] = acc;
    }
}

// ---------------------------------------------------------------------------
extern "C" void kernel_launch(void* const* d_in, const int* in_sizes, int n_in,
                              void* d_out, int out_size, void* d_ws, size_t ws_size,
                              hipStream_t stream) {
    const float* x     = (const float*)d_in[0];
    const int*   eidx  = (const int*)d_in[1];
    const int*   batch = (const int*)d_in[2];
    const float* w0 = (const float*)d_in[4];
    const float* b0 = (const float*)d_in[5];
    const float* g0 = (const float*)d_in[6];
    const float* be0 = (const float*)d_in[7];
    const float* m0 = (const float*)d_in[8];
    const float* v0 = (const float*)d_in[9];
    const float* w1 = (const float*)d_in[10];
    const float* b1 = (const float*)d_in[11];
    const float* g1 = (const float*)d_in[12];
    const float* be1 = (const float*)d_in[13];
    const float* m1 = (const float*)d_in[14];
    const float* v1 = (const float*)d_in[15];
    const float* w2 = (const float*)d_in[16];
    const float* b2 = (const float*)d_in[17];
    const float* g2 = (const float*)d_in[18];
    const float* be2 = (const float*)d_in[19];
    const float* m2 = (const float*)d_in[20];
    const float* v2 = (const float*)d_in[21];
    const float* fw0 = (const float*)d_in[22];
    const float* fb0 = (const float*)d_in[23];
    const float* fw1 = (const float*)d_in[24];
    const float* fb1 = (const float*)d_in[25];
    const float* ow = (const float*)d_in[26];
    const float* ob = (const float*)d_in[27];

    const int N = in_sizes[0] / 36;
    const int E = in_sizes[1] / 2;
    const int G = out_size / 2;
    const int* src = eidx;
    const int* dst = eidx + E;

    const int NB = (N + 255) / 256;               // node-scan blocks
    const int nbuck = (N + 511) >> BUCK_SHIFT;    // 512-node buckets (<=256)
    const int chunk = (E + PBLK - 1) / PBLK;
    const int nCounts = nbuck * PBLK;
    const int NBc = (nCounts + 255) / 256;        // counts-scan blocks (<=512)

    // ---- workspace layout (ebuf first for 8B alignment)
    char* wsb = (char*)d_ws;
    int2*  ebuf       = (int2*)wsb;                      wsb += (size_t)E * 8;
    int*   counts     = (int*)wsb;                       wsb += (size_t)nCounts * 4;
    int*   degI       = (int*)wsb;                       wsb += (size_t)N * 4;
    int*   row_start  = (int*)wsb;                       wsb += (size_t)N * 4;
    int*   bsum       = (int*)wsb;                       wsb += 512 * 4;
    int*   src_sorted = (int*)wsb;                       wsb += (size_t)E * 4;
    float* dinv       = (float*)wsb;                     wsb += (size_t)N * 4;
    float* A          = (float*)wsb;                     wsb += (size_t)N * 128 * 4;
    float* B          = (float*)wsb;                     wsb += (size_t)N * 128 * 4;
    float* pool       = (float*)wsb;                     wsb += (size_t)G * 64 * 4;
    float* cnt        = (float*)wsb;

    // ---- two-level counting sort -> bucket-grouped ebuf, then CSR
    bucket_hist<<<PBLK, 256, 0, stream>>>(dst, counts, E, nbuck, chunk);
    scan_block<<<NBc, 256, 0, stream>>>(counts, counts, bsum, nCounts);
    scan_bsum<<<1, 512, 0, stream>>>(bsum, NBc);
    scan_add<<<NBc, 256, 0, stream>>>(counts, bsum, nCounts);
    bucket_scatter<<<PBLK, 256, 0, stream>>>(src, dst, counts, ebuf, E, nbuck, chunk);
    bucket_degree<<<nbuck, 256, 0, stream>>>(ebuf, counts, degI, E, nbuck, N);
    dinv_kernel<<<NB, 256, 0, stream>>>(degI, dinv, N);
    scan_block<<<NB, 256, 0, stream>>>(degI, row_start, bsum, N);
    scan_bsum<<<1, 512, 0, stream>>>(bsum, NB);
    scan_add<<<NB, 256, 0, stream>>>(row_start, bsum, N);
    bucket_fill<<<nbuck, 256, 0, stream>>>(ebuf, counts, row_start, src_sorted, E, nbuck, N);

    const int NW = (N + 3) / 4;     // wave-per-node grid (4 waves/block)
    const int NG = (N + 63) / 64;   // gemm grid (64 rows/block)

    // ---- layer 0: xs = dinv.*x (stored in B), pull 36-ch (B -> A),
    //      GEMM 36->128 +BN+ReLU, output scaled by dinv (A -> B)
    {
        unsigned total = (unsigned)N * 36u;
        prescale36<<<(total + 255) / 256, 256, 0, stream>>>(x, dinv, B, N);
    }
    agg_pull36w<<<NW, 256, 0, stream>>>(B, row_start, degI, src_sorted, dinv, A, N);
    gemm_rt<36, 128, true, true><<<NG, 256, 0, stream>>>(A, w0, b0, g0, be0, m0, v0, dinv, B, N);

    // ---- layer 1: pull 128-ch scaled (B -> A), GEMM 128->128 +BN+ReLU unscaled (A -> B)
    agg_pull_wave<2><<<NW, 256, 0, stream>>>(B, row_start, degI, src_sorted, dinv, A, N);
    gemm_rt<128, 128, true, false><<<NG, 256, 0, stream>>>(A, w1, b1, g1, be1, m1, v1, nullptr, B, N);

    // ---- layer 2: GEMM 128->64 raw, output scaled (B -> A); pull 64-ch (A -> B)
    gemm_rt<128, 64, false, true><<<NG, 256, 0, stream>>>(B, w2, nullptr, nullptr, nullptr, nullptr, nullptr, dinv, A, N);
    agg_pull_wave<1><<<NW, 256, 0, stream>>>(A, row_start, degI, src_sorted, dinv, B, N);

    // ---- pool (mean over batch) with fused bias+BN+ReLU
    hipMemsetAsync(pool, 0, (size_t)G * 64 * 4, stream);
    hipMemsetAsync(cnt, 0, (size_t)G * 4, stream);
    count_kernel<<<NB, 256, 0, stream>>>(batch, cnt, N);
    {
        unsigned total = (unsigned)N * 64u;
        final_node_kernel<<<(total + 255) / 256, 256, 0, stream>>>(B, b2, g2, be2, m2, v2, batch, pool, N);
    }

    // ---- MLP head
    fc_head_kernel<<<G, 128, 0, stream>>>(pool, cnt, fw0, fb0, fw1, fb1, ow, ob, (float*)d_out);
}